// Round 1
// baseline (1952.778 us; speedup 1.0000x reference)
//
#include <hip/hip_runtime.h>

// ---------------- problem constants ----------------
#define NDIST   45
#define NANG    7
#define NTOW    52          // 45 dist + 7 angle towers
#define NSLICE  64          // workgroups per tower
#define BF      128         // frames per frame-block
#define NFBLK   32          // frame-blocks per workgroup  (262144/BF/NSLICE)
#define HSTRIDE 136         // f16 elements per LDS row (128 + 8 pad -> 272B, 2-way-free banks)

typedef _Float16 f16;
typedef _Float16 f16x2 __attribute__((ext_vector_type(2)));
typedef _Float16 f16x4 __attribute__((ext_vector_type(4)));
typedef _Float16 f16x8 __attribute__((ext_vector_type(8)));
typedef float    f32x4 __attribute__((ext_vector_type(4)));

__device__ __forceinline__ f16x2 splat2(float v) { f16x2 r; r[0] = (f16)v; r[1] = (f16)v; return r; }

// tanh(x) ~= xc * P(xc^2), xc = clamp(x, +-2.6); degree-4 Horner, |err| < ~0.013 (incl. clamp tail).
// Error budget is enormous here (NN total ~1e5 vs 2.6e10 threshold).
__device__ __forceinline__ f16x2 tanh_pk(f16x2 x) {
  x = __builtin_elementwise_max(x, splat2(-2.6f));
  x = __builtin_elementwise_min(x, splat2( 2.6f));
  f16x2 u = x * x;
  f16x2 p = u * splat2(0.00053778f) + splat2(-0.01005094f);
  p = u * p + splat2(0.07382459f);
  p = u * p + splat2(-0.29688618f);
  p = u * p + splat2(0.99552470f);
  return x * p;
}

// MFMA 16x16x32 f16 layout assumptions (gfx950, per guide §3 / m89/m91/m156):
//   A-frag: lane l supplies A[m = l&15][k = 32*ks + 8*(l>>4) + j], j=0..7  (one ds_read_b128)
//   B-frag: lane l supplies B[k = 32*ks + 8*(l>>4) + j][n = l&15]
//   D:      lane l, reg r holds D[m = 4*(l>>4) + r][n = l&15]
// We compute D[m_out][frame] = sum_k Wt[m_out][k] * H[frame][k]  (A = W^T, B = H^T),
// so each wave owns a 16-frame strip and D writes land back on the SAME strip rows.

__global__ __launch_bounds__(512, 2)
void towers_kernel(const float* __restrict__ F_dist, const float* __restrict__ F_cos,
                   const float* __restrict__ F_sin,
                   const float* __restrict__ Zd,  const float* __restrict__ Zc,
                   const float* __restrict__ Zs,
                   const float* __restrict__ W1d, const float* __restrict__ b1d,
                   const float* __restrict__ Whd, const float* __restrict__ bhd,
                   const float* __restrict__ Wod, const float* __restrict__ bod,
                   const float* __restrict__ W1a, const float* __restrict__ b1a,
                   const float* __restrict__ Wha, const float* __restrict__ bha,
                   const float* __restrict__ Woa, const float* __restrict__ boa,
                   float* __restrict__ out)
{
  __shared__ __align__(16) f16 H0[2][BF * HSTRIDE];   // layer-0 activations (double buffer)
  __shared__ __align__(16) f16 H1[2][BF * HSTRIDE];   // layer-1 activations (double buffer; [0] also W-stage scratch)
  __shared__ __align__(16) f16   sW1x[128];
  __shared__ __align__(16) f16   sW1y[128];
  __shared__ __align__(16) f16   sB1[128];
  __shared__ __align__(16) float sBh0[128];
  __shared__ __align__(16) float sBh1[128];
  __shared__ __align__(16) f16   sWo[128];
  __shared__ float sRed[8];
  __shared__ float sScal[8];

  const int tid  = threadIdx.x;
  const int wid  = tid >> 6;
  const int lane = tid & 63;
  const int T     = blockIdx.x / NSLICE;
  const int slice = blockIdx.x - T * NSLICE;
  const bool isDist = (T < NDIST);
  const int Ai = T - NDIST;

  // ---- stage small per-tower params ----
  if (tid < 128) {
    const int n = tid;
    float w1x, w1y, b1v, bh0v, bh1v, wov;
    if (isDist) {
      w1x  = W1d[T * 128 + n];              w1y = 0.f;
      b1v  = b1d[T * 128 + n];
      bh0v = bhd[(0 * NDIST + T) * 128 + n];
      bh1v = bhd[(1 * NDIST + T) * 128 + n];
      wov  = Wod[T * 128 + n];
    } else {
      w1x  = W1a[(Ai * 2 + 0) * 128 + n];
      w1y  = W1a[(Ai * 2 + 1) * 128 + n];
      b1v  = b1a[Ai * 128 + n];
      bh0v = bha[(0 * NANG + Ai) * 128 + n];
      bh1v = bha[(1 * NANG + Ai) * 128 + n];
      wov  = Woa[Ai * 128 + n];
    }
    sW1x[n] = (f16)w1x; sW1y[n] = (f16)w1y; sB1[n] = (f16)b1v;
    sBh0[n] = bh0v; sBh1[n] = bh1v; sWo[n] = (f16)wov;
  }
  if (tid == 0) {
    if (isDist) {
      sScal[0] = Zd[T];  sScal[1] = 1.f / Zd[NDIST + T];
      sScal[2] = 0.f;    sScal[3] = 0.f;
      sScal[4] = bod[T];
    } else {
      sScal[0] = Zc[0];  sScal[1] = 1.f / Zc[NANG];   // INDEX5 = zeros -> column 0 only
      sScal[2] = Zs[0];  sScal[3] = 1.f / Zs[NANG];
      sScal[4] = boa[Ai];
    }
  }
  __syncthreads();

  const float zm0 = sScal[0], zsi0 = sScal[1], zm1 = sScal[2], zsi1 = sScal[3];

  // ---- stage Wt = W^T (f16) per layer into H1[0]; group A keeps layer-0 hidden W, group B layer-1 ----
  const float* __restrict__ WhT = isDist ? (Whd + (size_t)T * 16384)
                                         : (Wha + (size_t)Ai * 16384);
  const size_t WhLstride = isDist ? (size_t)NDIST * 16384 : (size_t)NANG * 16384;

  f16x8 areg[8][4];   // full 128x128 W^T as A-fragments, persistent for the whole kernel
  #pragma unroll 1
  for (int l = 0; l < 2; ++l) {
    const float* __restrict__ src = WhT + (size_t)l * WhLstride;
    const int m = tid & 127;
    #pragma unroll 4
    for (int p = 0; p < 16; ++p) {
      const int n = 2 * ((tid >> 7) + 4 * p);            // even n; coalesced over m
      const float a0 = src[(size_t)n * 128 + m];         // Wh[l][tow][n][m]
      const float a1 = src[(size_t)(n + 1) * 128 + m];
      f16x2 v; v[0] = (f16)a0; v[1] = (f16)a1;
      *(f16x2*)&H1[0][m * HSTRIDE + n] = v;              // Wt[m][n]
    }
    __syncthreads();
    if ((wid < 4) == (l == 0)) {
      #pragma unroll
      for (int mt = 0; mt < 8; ++mt)
        #pragma unroll
        for (int ks = 0; ks < 4; ++ks)
          areg[mt][ks] = *(const f16x8*)&H1[0][(16 * mt + (lane & 15)) * HSTRIDE + 32 * ks + 8 * (lane >> 4)];
    }
    __syncthreads();
  }

  float waveY = 0.f;
  const int fb0 = slice * NFBLK;

  // ---- 3-stage pipeline over frame-blocks: layer0(it) || gemm1(it-1) || gemm2+out(it-2) ----
  #pragma unroll 1
  for (int it = 0; it < NFBLK + 2; ++it) {
    if (wid < 4) {
      // issue layer-0 input loads early (hidden under gemm1)
      float xr0[8], xr1[8];
      const int fq = tid >> 4;          // 0..15 (tid < 256)
      const int n0 = 8 * (tid & 15);
      if (it < NFBLK) {
        const size_t frame0 = (size_t)(fb0 + it) * BF;
        #pragma unroll
        for (int p = 0; p < 8; ++p) {
          const size_t gf = frame0 + 16 * p + fq;
          if (isDist) {
            xr0[p] = F_dist[gf * NDIST + T];
            xr1[p] = 0.f;
          } else {
            xr0[p] = F_cos[gf * NANG];
            xr1[p] = F_sin[gf * NANG];
          }
        }
      }
      // GEMM hidden layer 1 for fblock it-1 : H1 = tanh(H0 @ Wh0 + bh0)
      if (it >= 1 && it <= NFBLK) {
        const f16* __restrict__ Hr = H0[(it - 1) & 1];
        f16*       __restrict__ Hw = H1[(it - 1) & 1];
        const int g  = lane >> 4;
        const int fl = lane & 15;
        #pragma unroll 1
        for (int si = 0; si < 2; ++si) {
          const int fr = 16 * (wid + 4 * si) + fl;
          f16x8 breg[4];
          #pragma unroll
          for (int ks = 0; ks < 4; ++ks)
            breg[ks] = *(const f16x8*)&Hr[fr * HSTRIDE + 32 * ks + 8 * g];
          #pragma unroll
          for (int mt = 0; mt < 8; ++mt) {
            f32x4 acc = {0.f, 0.f, 0.f, 0.f};
            #pragma unroll
            for (int ks = 0; ks < 4; ++ks)
              acc = __builtin_amdgcn_mfma_f32_16x16x32_f16(areg[mt][ks], breg[ks], acc, 0, 0, 0);
            const float4 b4 = *(const float4*)&sBh0[16 * mt + 4 * g];
            f16x2 lo; lo[0] = (f16)(acc[0] + b4.x); lo[1] = (f16)(acc[1] + b4.y);
            f16x2 hi; hi[0] = (f16)(acc[2] + b4.z); hi[1] = (f16)(acc[3] + b4.w);
            lo = tanh_pk(lo); hi = tanh_pk(hi);
            f16x4 o; o[0] = lo[0]; o[1] = lo[1]; o[2] = hi[0]; o[3] = hi[1];
            *(f16x4*)&Hw[fr * HSTRIDE + 16 * mt + 4 * g] = o;   // H1[frame][k=m_out]
          }
        }
      }
      // finish layer 0 for fblock it : H0 = tanh(x*W1 + b1)
      if (it < NFBLK) {
        f16* __restrict__ Hw = H0[it & 1];
        const f16x8 w8  = *(const f16x8*)&sW1x[n0];
        const f16x8 w8y = *(const f16x8*)&sW1y[n0];
        const f16x8 b8  = *(const f16x8*)&sB1[n0];
        #pragma unroll
        for (int p = 0; p < 8; ++p) {
          const float x0 = (xr0[p] - zm0) * zsi0;
          const f16x2 xx = splat2(x0);
          f16x2 yy = splat2(0.f);
          if (!isDist) yy = splat2((xr1[p] - zm1) * zsi1);
          f16x8 h8;
          #pragma unroll
          for (int q = 0; q < 4; ++q) {
            f16x2 w2; w2[0] = w8[2 * q];  w2[1] = w8[2 * q + 1];
            f16x2 b2; b2[0] = b8[2 * q];  b2[1] = b8[2 * q + 1];
            f16x2 a = w2 * xx + b2;
            if (!isDist) {
              f16x2 wy; wy[0] = w8y[2 * q]; wy[1] = w8y[2 * q + 1];
              a = a + wy * yy;
            }
            f16x2 t = tanh_pk(a);
            h8[2 * q] = t[0]; h8[2 * q + 1] = t[1];
          }
          *(f16x8*)&Hw[(16 * p + fq) * HSTRIDE + n0] = h8;
        }
      }
    } else {
      // group B: GEMM hidden layer 2 + fused output dot for fblock it-2
      if (it >= 2) {
        const f16* __restrict__ Hr = H1[(it - 2) & 1];
        const int g  = lane >> 4;
        const int fl = lane & 15;
        #pragma unroll 1
        for (int si = 0; si < 2; ++si) {
          const int fr = 16 * ((wid - 4) + 4 * si) + fl;
          f16x8 breg[4];
          #pragma unroll
          for (int ks = 0; ks < 4; ++ks)
            breg[ks] = *(const f16x8*)&Hr[fr * HSTRIDE + 32 * ks + 8 * g];
          f16x2 y2 = splat2(0.f);
          #pragma unroll
          for (int mt = 0; mt < 8; ++mt) {
            f32x4 acc = {0.f, 0.f, 0.f, 0.f};
            #pragma unroll
            for (int ks = 0; ks < 4; ++ks)
              acc = __builtin_amdgcn_mfma_f32_16x16x32_f16(areg[mt][ks], breg[ks], acc, 0, 0, 0);
            const float4 b4 = *(const float4*)&sBh1[16 * mt + 4 * g];
            f16x2 lo; lo[0] = (f16)(acc[0] + b4.x); lo[1] = (f16)(acc[1] + b4.y);
            f16x2 hi; hi[0] = (f16)(acc[2] + b4.z); hi[1] = (f16)(acc[3] + b4.w);
            lo = tanh_pk(lo); hi = tanh_pk(hi);
            const f16x4 wo4 = *(const f16x4*)&sWo[16 * mt + 4 * g];
            f16x2 wlo; wlo[0] = wo4[0]; wlo[1] = wo4[1];
            f16x2 whi; whi[0] = wo4[2]; whi[1] = wo4[3];
            y2 = y2 + lo * wlo;
            y2 = y2 + hi * whi;
          }
          float y = (float)y2[0] + (float)y2[1];
          y += __shfl_xor(y, 16, 64);   // sum over k-quads (g)
          y += __shfl_xor(y, 32, 64);
          y += __shfl_xor(y, 8, 64);    // sum over the strip's 16 frames
          y += __shfl_xor(y, 4, 64);
          y += __shfl_xor(y, 2, 64);
          y += __shfl_xor(y, 1, 64);
          waveY += y;
        }
      }
    }
    __syncthreads();
  }

  if (wid >= 4 && lane == 0) sRed[wid] = waveY;
  __syncthreads();
  if (tid == 0) {
    float tot = sRed[4] + sRed[5] + sRed[6] + sRed[7];
    tot += sScal[4] * (float)(BF * NFBLK);   // + bo per frame
    atomicAdd(out, tot);
  }
}

// ---------------- bond + repel (memory-light, ~15us) ----------------
__global__ __launch_bounds__(256)
void bond_repel_kernel(const float* __restrict__ Fd, const float* __restrict__ Fa,
                       const float* __restrict__ BC, float* __restrict__ out)
{
  __shared__ float sd[256 * NDIST];
  __shared__ float sa[256 * NANG];
  __shared__ float sred[4];
  const int tid = threadIdx.x;
  const size_t b0 = (size_t)blockIdx.x * 256;
  for (int k = tid; k < 256 * NDIST; k += 256) sd[k] = Fd[b0 * NDIST + k];
  for (int k = tid; k < 256 * NANG;  k += 256) sa[k] = Fa[b0 * NANG + k];
  __syncthreads();
  const float* d = &sd[tid * NDIST];
  const float* a = &sa[tid * NANG];
  float bond = 0.f;
  #pragma unroll
  for (int j = 0; j < 9; ++j) { float t = d[j] - BC[16 + j];     bond += BC[j] * t * t; }
  #pragma unroll
  for (int j = 0; j < 7; ++j) { float t = a[j] - BC[16 + 9 + j]; bond += BC[9 + j] * t * t; }
  float repel = 0.f;
  #pragma unroll
  for (int j = 17; j < 45; ++j) {
    const float v = d[j];
    const float v2 = v * v;
    const float v6 = v2 * v2 * v2;
    repel += 27680.640625f / v6;   // 5.5^6 / d^6
  }
  float u = 0.5f * bond + repel;
  #pragma unroll
  for (int off = 32; off >= 1; off >>= 1) u += __shfl_xor(u, off, 64);
  if ((tid & 63) == 0) sred[tid >> 6] = u;
  __syncthreads();
  if (tid == 0) atomicAdd(out, sred[0] + sred[1] + sred[2] + sred[3]);
}

extern "C" void kernel_launch(void* const* d_in, const int* in_sizes, int n_in,
                              void* d_out, int out_size, void* d_ws, size_t ws_size,
                              hipStream_t stream)
{
  (void)in_sizes; (void)n_in; (void)d_ws; (void)ws_size; (void)out_size;
  const float* F_dist  = (const float*)d_in[0];
  const float* F_cos   = (const float*)d_in[1];
  const float* F_sin   = (const float*)d_in[2];
  const float* F_angle = (const float*)d_in[3];
  const float* Zd      = (const float*)d_in[4];
  const float* Zc      = (const float*)d_in[5];
  const float* Zs      = (const float*)d_in[6];
  const float* BC      = (const float*)d_in[7];
  const float* W1d     = (const float*)d_in[8];
  const float* b1d     = (const float*)d_in[9];
  const float* Whd     = (const float*)d_in[10];
  const float* bhd     = (const float*)d_in[11];
  const float* Wod     = (const float*)d_in[12];
  const float* bod     = (const float*)d_in[13];
  const float* W1a     = (const float*)d_in[14];
  const float* b1a     = (const float*)d_in[15];
  const float* Wha     = (const float*)d_in[16];
  const float* bha     = (const float*)d_in[17];
  const float* Woa     = (const float*)d_in[18];
  const float* boa     = (const float*)d_in[19];
  float* out = (float*)d_out;

  hipMemsetAsync(d_out, 0, sizeof(float), stream);
  bond_repel_kernel<<<dim3(262144 / 256), dim3(256), 0, stream>>>(F_dist, F_angle, BC, out);
  towers_kernel<<<dim3(NTOW * NSLICE), dim3(512), 0, stream>>>(
      F_dist, F_cos, F_sin, Zd, Zc, Zs,
      W1d, b1d, Whd, bhd, Wod, bod,
      W1a, b1a, Wha, bha, Woa, boa, out);
}

// Round 2
// 1588.938 us; speedup vs baseline: 1.2290x; 1.2290x over previous
//
#include <hip/hip_runtime.h>

// ---------------- problem constants ----------------
#define NDIST   45
#define NANG    7
#define NTOW    52          // 45 dist + 7 angle towers
#define NSLICE  64          // workgroups per tower -> grid 3328 = 13 exact rounds on 256 CUs
#define BF      128         // frames per frame-block
#define NFBLK   32          // frame-blocks per workgroup  (262144/BF/NSLICE)
#define HSTRIDE 136         // f16 elements per LDS row (128 + 8 pad)

typedef _Float16 f16;
typedef _Float16 f16x2 __attribute__((ext_vector_type(2)));
typedef _Float16 f16x4 __attribute__((ext_vector_type(4)));
typedef _Float16 f16x8 __attribute__((ext_vector_type(8)));
typedef float    f32x4 __attribute__((ext_vector_type(4)));

__device__ __forceinline__ f16x2 splat2(float v) { f16x2 r; r[0] = (f16)v; r[1] = (f16)v; return r; }
__device__ __forceinline__ f16x2 pkrtz(float a, float b) {
  return __builtin_bit_cast(f16x2, __builtin_amdgcn_cvt_pkrtz(a, b));
}

// tanh(x) ~= xc * P(xc^2), xc = clamp(x, +-2.6); degree-4 Horner (8 pk insts).
__device__ __forceinline__ f16x2 tanh_pk(f16x2 x) {
  x = __builtin_elementwise_max(x, splat2(-2.6f));
  x = __builtin_elementwise_min(x, splat2( 2.6f));
  f16x2 u = x * x;
  f16x2 p = u * splat2(0.00053778f) + splat2(-0.01005094f);
  p = u * p + splat2(0.07382459f);
  p = u * p + splat2(-0.29688618f);
  p = u * p + splat2(0.99552470f);
  return x * p;
}

// MFMA 16x16x32 f16 layout (verified round 1, absmax 0):
//   A-frag: lane l supplies A[m = l&15][k = 32*ks + 8*(l>>4) + j], j=0..7
//   B-frag: lane l supplies B[k = 32*ks + 8*(l>>4) + j][n = l&15]
//   D:      lane l, reg r holds D[m = 4*(l>>4) + r][n = l&15]
// Half-split waves: wave w holds rows [64*(w&1), 64*(w&1)+64) of BOTH layers'
// W^T as A-fragments (areg1, areg2 = 128 VGPRs). Wave pair (2s,2s+1) covers a
// 16-frame strip; each wave computes its 64 output rows for gemm1 AND gemm2,
// plus an equal share of layer0 -> all 8 waves do identical work per phase.

__global__ __launch_bounds__(512, 2)
void towers_kernel(const float* __restrict__ F_dist, const float* __restrict__ F_cos,
                   const float* __restrict__ F_sin,
                   const float* __restrict__ Zd,  const float* __restrict__ Zc,
                   const float* __restrict__ Zs,  const float* __restrict__ BC,
                   const float* __restrict__ W1d, const float* __restrict__ b1d,
                   const float* __restrict__ Whd, const float* __restrict__ bhd,
                   const float* __restrict__ Wod, const float* __restrict__ bod,
                   const float* __restrict__ W1a, const float* __restrict__ b1a,
                   const float* __restrict__ Wha, const float* __restrict__ bha,
                   const float* __restrict__ Woa, const float* __restrict__ boa,
                   float* __restrict__ out)
{
  __shared__ __align__(16) f16 H0[2][BF * HSTRIDE];   // layer-0 activations (double buffer)
  __shared__ __align__(16) f16 H1[2][BF * HSTRIDE];   // layer-1 activations ([0] also W-stage scratch)
  __shared__ __align__(16) f16 sW1x[128], sW1y[128], sB1[128];
  __shared__ float sScal[8];
  __shared__ float sRed[8];

  const int tid  = threadIdx.x;
  const int wid  = tid >> 6;
  const int lane = tid & 63;
  const int fl   = lane & 15;
  const int g    = lane >> 4;
  const int h    = wid & 1;        // which 64-row half of W this wave owns
  const int ps   = wid >> 1;       // strip pair id: strips {ps, ps+4}
  const int T     = blockIdx.x / NSLICE;
  const int slice = blockIdx.x - T * NSLICE;
  const bool isDist = (T < NDIST);
  const int Ai = T - NDIST;

  // ---- stage layer-0 params ----
  if (tid < 128) {
    const int n = tid;
    float w1x, w1y, b1v;
    if (isDist) { w1x = W1d[T*128+n]; w1y = 0.f; b1v = b1d[T*128+n]; }
    else { w1x = W1a[(Ai*2+0)*128+n]; w1y = W1a[(Ai*2+1)*128+n]; b1v = b1a[Ai*128+n]; }
    sW1x[n] = (f16)w1x; sW1y[n] = (f16)w1y; sB1[n] = (f16)b1v;
  }
  if (tid == 0) {
    if (isDist) { sScal[0]=Zd[T]; sScal[1]=1.f/Zd[NDIST+T]; sScal[2]=0.f; sScal[3]=0.f; sScal[4]=bod[T]; }
    else { sScal[0]=Zc[0]; sScal[1]=1.f/Zc[NANG]; sScal[2]=Zs[0]; sScal[3]=1.f/Zs[NANG]; sScal[4]=boa[Ai]; }
  }

  // ---- per-wave constants in registers: biases as MFMA C-init, wo as pk f16 ----
  const int rb = 64*h + 4*g;       // D row base (+16*mt+r)
  const float* __restrict__ bh0p = isDist ? (bhd + (size_t)(0*NDIST+T)*128) : (bha + (size_t)(0*NANG+Ai)*128);
  const float* __restrict__ bh1p = isDist ? (bhd + (size_t)(1*NDIST+T)*128) : (bha + (size_t)(1*NANG+Ai)*128);
  const float* __restrict__ wop  = isDist ? (Wod + (size_t)T*128) : (Woa + (size_t)Ai*128);
  f32x4 bias1[4], bias2[4];
  f16x2 wlo[4], whi[4];
  #pragma unroll
  for (int mt = 0; mt < 4; ++mt) {
    bias1[mt] = *(const f32x4*)&bh0p[rb + 16*mt];
    bias2[mt] = *(const f32x4*)&bh1p[rb + 16*mt];
    const f32x4 w4 = *(const f32x4*)&wop[rb + 16*mt];
    wlo[mt] = pkrtz(w4[0], w4[1]);
    whi[mt] = pkrtz(w4[2], w4[3]);
  }

  // ---- stage Wt = W^T (f16) per layer into H1[0]; every wave grabs its 64-row half ----
  const float* __restrict__ WhB = isDist ? (Whd + (size_t)T*16384) : (Wha + (size_t)Ai*16384);
  const size_t Wls = isDist ? (size_t)NDIST*16384 : (size_t)NANG*16384;
  f16x8 areg1[4][4], areg2[4][4];

  auto stageW = [&](const float* __restrict__ src) {
    const int m = tid & 127;
    #pragma unroll 4
    for (int p = 0; p < 16; ++p) {
      const int n = 2*((tid >> 7) + 4*p);
      f16x2 v; v[0] = (f16)src[(size_t)n*128 + m]; v[1] = (f16)src[(size_t)(n+1)*128 + m];
      *(f16x2*)&H1[0][m*HSTRIDE + n] = v;              // Wt[m][n]
    }
  };
  stageW(WhB);
  __syncthreads();
  #pragma unroll
  for (int mt = 0; mt < 4; ++mt)
    #pragma unroll
    for (int ks = 0; ks < 4; ++ks)
      areg1[mt][ks] = *(const f16x8*)&H1[0][(64*h + 16*mt + fl)*HSTRIDE + 32*ks + 8*g];
  __syncthreads();
  stageW(WhB + Wls);
  __syncthreads();
  #pragma unroll
  for (int mt = 0; mt < 4; ++mt)
    #pragma unroll
    for (int ks = 0; ks < 4; ++ks)
      areg2[mt][ks] = *(const f16x8*)&H1[0][(64*h + 16*mt + fl)*HSTRIDE + 32*ks + 8*g];
  __syncthreads();

  const float zm0 = sScal[0], zsi0 = sScal[1], zm1 = sScal[2], zsi1 = sScal[3];
  const int n0 = 8*(tid & 15);
  const int fq = tid >> 4;                 // 0..31
  const f16x8 w8  = *(const f16x8*)&sW1x[n0];
  const f16x8 w8y = *(const f16x8*)&sW1y[n0];
  const f16x8 b8  = *(const f16x8*)&sB1[n0];

  // bond/repel fold (each frame's column value loaded by 16 threads -> scale 1/16)
  float bK = 0.f, bEq = 0.f;
  if (isDist && T < 9) { bK = 0.03125f * BC[T]; bEq = BC[16 + T]; }   // 0.5/16 * k
  const bool doRep = isDist && (T >= 17);

  float accY = 0.f;
  const int fb0 = slice * NFBLK;

  // ---- 3-stage pipeline, 1 barrier per 128-frame block ----
  #pragma unroll 1
  for (int it = 0; it < NFBLK + 2; ++it) {
    // issue layer-0 input loads early (hidden under the GEMMs)
    float xr0[4], xr1[4];
    if (it < NFBLK) {
      const size_t frame0 = (size_t)(fb0 + it) * BF;
      #pragma unroll
      for (int p = 0; p < 4; ++p) {
        const size_t gf = frame0 + fq + 32*p;
        if (isDist) { xr0[p] = F_dist[gf*NDIST + T]; xr1[p] = 0.f; }
        else        { xr0[p] = F_cos[gf*NANG];       xr1[p] = F_sin[gf*NANG]; }
      }
    }
    // gemm2(it-2): H1[(it-2)&1] -> per-lane output partial
    if (it >= 2) {
      const f16* __restrict__ Hr = H1[it & 1];
      #pragma unroll
      for (int si = 0; si < 2; ++si) {
        const int fr = 16*(ps + 4*si) + fl;
        const f16* __restrict__ hp = Hr + fr*HSTRIDE + 8*g;
        f16x8 breg[4];
        #pragma unroll
        for (int ks = 0; ks < 4; ++ks) breg[ks] = *(const f16x8*)(hp + 32*ks);
        f16x2 y2 = splat2(0.f);
        #pragma unroll
        for (int mt = 0; mt < 4; ++mt) {
          f32x4 acc = bias2[mt];
          #pragma unroll
          for (int ks = 0; ks < 4; ++ks)
            acc = __builtin_amdgcn_mfma_f32_16x16x32_f16(areg2[mt][ks], breg[ks], acc, 0, 0, 0);
          f16x2 lo = tanh_pk(pkrtz(acc[0], acc[1]));
          f16x2 hi = tanh_pk(pkrtz(acc[2], acc[3]));
          y2 = y2 + lo * wlo[mt];
          y2 = y2 + hi * whi[mt];
        }
        accY += (float)y2[0] + (float)y2[1];
      }
    }
    // gemm1(it-1): H0[(it-1)&1] -> H1[(it-1)&1]
    if (it >= 1 && it <= NFBLK) {
      const f16* __restrict__ Hr = H0[(it-1) & 1];
      f16*       __restrict__ Hw = H1[(it-1) & 1];
      #pragma unroll
      for (int si = 0; si < 2; ++si) {
        const int fr = 16*(ps + 4*si) + fl;
        const f16* __restrict__ hp = Hr + fr*HSTRIDE + 8*g;
        f16x8 breg[4];
        #pragma unroll
        for (int ks = 0; ks < 4; ++ks) breg[ks] = *(const f16x8*)(hp + 32*ks);
        f16* __restrict__ wp = Hw + fr*HSTRIDE + rb;
        #pragma unroll
        for (int mt = 0; mt < 4; ++mt) {
          f32x4 acc = bias1[mt];
          #pragma unroll
          for (int ks = 0; ks < 4; ++ks)
            acc = __builtin_amdgcn_mfma_f32_16x16x32_f16(areg1[mt][ks], breg[ks], acc, 0, 0, 0);
          f16x2 lo = tanh_pk(pkrtz(acc[0], acc[1]));
          f16x2 hi = tanh_pk(pkrtz(acc[2], acc[3]));
          f16x4 o; o[0] = lo[0]; o[1] = lo[1]; o[2] = hi[0]; o[3] = hi[1];
          *(f16x4*)(wp + 16*mt) = o;                    // H1[frame][m_out]
        }
      }
    }
    // layer0(it): x -> H0[it&1], plus folded bond/repel on raw x
    if (it < NFBLK) {
      f16* __restrict__ Hw = H0[it & 1];
      #pragma unroll
      for (int p = 0; p < 4; ++p) {
        const float xraw = xr0[p];
        if (bK != 0.f) { const float t = xraw - bEq; accY += bK * t * t; }
        if (doRep) {
          const float v2 = xraw * xraw;
          const float v6 = v2 * v2 * v2;
          accY += 1730.0400390625f * __builtin_amdgcn_rcpf(v6);   // 5.5^6/16 / d^6
        }
        const f16x2 xn = pkrtz((xraw - zm0) * zsi0, (xraw - zm0) * zsi0);
        f16x2 yn;
        if (!isDist) { const float ys = (xr1[p] - zm1) * zsi1; yn = pkrtz(ys, ys); }
        f16x8 h8;
        #pragma unroll
        for (int q = 0; q < 4; ++q) {
          f16x2 w2; w2[0] = w8[2*q];  w2[1] = w8[2*q+1];
          f16x2 b2; b2[0] = b8[2*q];  b2[1] = b8[2*q+1];
          f16x2 a = w2 * xn + b2;
          if (!isDist) { f16x2 wy; wy[0] = w8y[2*q]; wy[1] = w8y[2*q+1]; a = a + wy * yn; }
          f16x2 t = tanh_pk(a);
          h8[2*q] = t[0]; h8[2*q+1] = t[1];
        }
        *(f16x8*)&Hw[(fq + 32*p)*HSTRIDE + n0] = h8;
      }
    }
    __syncthreads();
  }

  // ---- single reduction at the end ----
  #pragma unroll
  for (int off = 1; off < 64; off <<= 1) accY += __shfl_xor(accY, off, 64);
  if (lane == 0) sRed[wid] = accY;
  __syncthreads();
  if (tid == 0) {
    float tot = sRed[0] + sRed[1] + sRed[2] + sRed[3] + sRed[4] + sRed[5] + sRed[6] + sRed[7];
    tot += sScal[4] * (float)(BF * NFBLK);   // + bo per frame
    atomicAdd(out, tot);
  }
}

// ---------------- angle-only bond (F_dist terms folded into towers_kernel) ----------------
__global__ __launch_bounds__(256)
void angle_bond_kernel(const float* __restrict__ Fa, const float* __restrict__ BC,
                       float* __restrict__ out)
{
  __shared__ float sa[256 * NANG];
  __shared__ float sred[4];
  const int tid = threadIdx.x;
  const size_t b0 = (size_t)blockIdx.x * 256;
  for (int k = tid; k < 256 * NANG; k += 256) sa[k] = Fa[b0 * NANG + k];
  __syncthreads();
  const float* a = &sa[tid * NANG];
  float bond = 0.f;
  #pragma unroll
  for (int j = 0; j < 7; ++j) { float t = a[j] - BC[16 + 9 + j]; bond += BC[9 + j] * t * t; }
  float u = 0.5f * bond;
  #pragma unroll
  for (int off = 32; off >= 1; off >>= 1) u += __shfl_xor(u, off, 64);
  if ((tid & 63) == 0) sred[tid >> 6] = u;
  __syncthreads();
  if (tid == 0) atomicAdd(out, sred[0] + sred[1] + sred[2] + sred[3]);
}

extern "C" void kernel_launch(void* const* d_in, const int* in_sizes, int n_in,
                              void* d_out, int out_size, void* d_ws, size_t ws_size,
                              hipStream_t stream)
{
  (void)in_sizes; (void)n_in; (void)d_ws; (void)ws_size; (void)out_size;
  const float* F_dist  = (const float*)d_in[0];
  const float* F_cos   = (const float*)d_in[1];
  const float* F_sin   = (const float*)d_in[2];
  const float* F_angle = (const float*)d_in[3];
  const float* Zd      = (const float*)d_in[4];
  const float* Zc      = (const float*)d_in[5];
  const float* Zs      = (const float*)d_in[6];
  const float* BC      = (const float*)d_in[7];
  const float* W1d     = (const float*)d_in[8];
  const float* b1d     = (const float*)d_in[9];
  const float* Whd     = (const float*)d_in[10];
  const float* bhd     = (const float*)d_in[11];
  const float* Wod     = (const float*)d_in[12];
  const float* bod     = (const float*)d_in[13];
  const float* W1a     = (const float*)d_in[14];
  const float* b1a     = (const float*)d_in[15];
  const float* Wha     = (const float*)d_in[16];
  const float* bha     = (const float*)d_in[17];
  const float* Woa     = (const float*)d_in[18];
  const float* boa     = (const float*)d_in[19];
  float* out = (float*)d_out;

  hipMemsetAsync(d_out, 0, sizeof(float), stream);
  angle_bond_kernel<<<dim3(262144 / 256), dim3(256), 0, stream>>>(F_angle, BC, out);
  towers_kernel<<<dim3(NTOW * NSLICE), dim3(512), 0, stream>>>(
      F_dist, F_cos, F_sin, Zd, Zc, Zs, BC,
      W1d, b1d, Whd, bhd, Wod, bod,
      W1a, b1a, Wha, bha, Woa, boa, out);
}